// Round 1
// baseline (2040.452 us; speedup 1.0000x reference)
//
#include <hip/hip_runtime.h>
#include <math.h>

#define NP 2048           // points per batch (n == m)
#define DF 256            // feature dim
#define NPROB 8           // 2 OTs * 4 batches
#define NTOT 8192         // total rows per feature tensor

constexpr float F_MU   = 1.0f / 2048.0f;   // uniform marginal 1/n
constexpr float F_STAB = 1e-8f;

// workspace layout (in floats)
constexpr size_t OFF_K   = 0;
constexpr size_t SZ_K    = (size_t)NPROB * NP * NP;     // 33,554,432
constexpr size_t OFF_VA  = OFF_K + SZ_K;                // 3 ping-pong-pong buffers
constexpr size_t SZ_VA   = (size_t)3 * NPROB * NP;      // 49,152
constexpr size_t OFF_U   = OFF_VA + SZ_VA;
constexpr size_t SZ_U    = (size_t)NPROB * NP;          // 16,384
constexpr size_t OFF_INV = OFF_U + SZ_U;
constexpr size_t SZ_INV  = (size_t)3 * NTOT;            // 24,576
constexpr size_t OFF_SUM = OFF_INV + SZ_INV;            // 1 float

// ---------------------------------------------------------------- row norms
__global__ __launch_bounds__(256) void k_norms(const float* __restrict__ src,
                                               const float* __restrict__ tgt,
                                               const float* __restrict__ gen,
                                               float* __restrict__ inv) {
    int gw   = (blockIdx.x * 256 + threadIdx.x) >> 6;   // 0 .. 3*8192-1
    int lane = threadIdx.x & 63;
    int a = gw >> 13;          // which tensor
    int r = gw & 8191;         // row
    const float* base = (a == 0 ? src : (a == 1 ? tgt : gen)) + (size_t)r * DF;
    float4 x = reinterpret_cast<const float4*>(base)[lane];   // 64 lanes * 4 = 256
    float s = x.x * x.x + x.y * x.y + x.z * x.z + x.w * x.w;
    #pragma unroll
    for (int off = 32; off; off >>= 1) s += __shfl_xor(s, off);
    if (lane == 0) inv[gw] = 1.0f / (sqrtf(s) + F_STAB);
}

// ---------------------------------------------------------------- zero init
__global__ void k_init(float* __restrict__ va0, float* __restrict__ sum) {
    int i = blockIdx.x * 256 + threadIdx.x;
    if (i < NPROB * NP) va0[i] = 0.0f;
    if (i == 0) sum[0] = 0.0f;
}

// ---------------------------------------------------------------- K = exp(cos-1)
// 128x128 tile per block, 8x8 micro-tile per thread (strided rows/cols so LDS
// reads are conflict-free with the +1 pad). f32 vector FMA (no fp32 MFMA).
#define TK 16
__global__ __launch_bounds__(256) void k_build(const float* __restrict__ src,
                                               const float* __restrict__ tgt,
                                               const float* __restrict__ gen,
                                               const float* __restrict__ inv,
                                               float* __restrict__ K) {
    __shared__ float As[128][TK + 1];
    __shared__ float Bs[128][TK + 1];
    int bid = blockIdx.x;          // 2048 = 8 problems * 16 * 16 tiles
    int p   = bid >> 8;
    int t   = bid & 255;
    int ti  = t >> 4, tj = t & 15;
    int ot  = p >> 2, b = p & 3;
    const float* X    = (ot == 0) ? src : tgt;
    const float* Y    = (ot == 0) ? tgt : gen;
    const float* invx = inv + (ot == 0 ? 0 : NTOT);
    const float* invy = inv + (ot == 0 ? NTOT : 2 * NTOT);
    int rowA0 = b * NP + ti * 128;
    int rowB0 = b * NP + tj * 128;

    int tid = threadIdx.x;
    int ty  = tid >> 4, tx = tid & 15;

    float acc[8][8];
    #pragma unroll
    for (int i = 0; i < 8; ++i)
        #pragma unroll
        for (int j = 0; j < 8; ++j) acc[i][j] = 0.0f;

    for (int kb = 0; kb < DF; kb += TK) {
        __syncthreads();
        #pragma unroll
        for (int s = 0; s < 2; ++s) {
            int j4  = tid + s * 256;         // 0..511 over 128x16 tile
            int row = j4 >> 2;
            int c4  = (j4 & 3) * 4;
            float4 av = *reinterpret_cast<const float4*>(X + (size_t)(rowA0 + row) * DF + kb + c4);
            float  sa = invx[rowA0 + row];
            As[row][c4 + 0] = av.x * sa; As[row][c4 + 1] = av.y * sa;
            As[row][c4 + 2] = av.z * sa; As[row][c4 + 3] = av.w * sa;
            float4 bv = *reinterpret_cast<const float4*>(Y + (size_t)(rowB0 + row) * DF + kb + c4);
            float  sb = invy[rowB0 + row];
            Bs[row][c4 + 0] = bv.x * sb; Bs[row][c4 + 1] = bv.y * sb;
            Bs[row][c4 + 2] = bv.z * sb; Bs[row][c4 + 3] = bv.w * sb;
        }
        __syncthreads();
        #pragma unroll
        for (int kk = 0; kk < TK; ++kk) {
            float a[8], bb[8];
            #pragma unroll
            for (int i = 0; i < 8; ++i) a[i]  = As[ty + 16 * i][kk];
            #pragma unroll
            for (int j = 0; j < 8; ++j) bb[j] = Bs[tx + 16 * j][kk];
            #pragma unroll
            for (int i = 0; i < 8; ++i)
                #pragma unroll
                for (int j = 0; j < 8; ++j) acc[i][j] += a[i] * bb[j];
        }
    }

    float* Kp = K + (size_t)p * NP * NP;
    #pragma unroll
    for (int i = 0; i < 8; ++i) {
        int gi = ti * 128 + ty + 16 * i;
        #pragma unroll
        for (int j = 0; j < 8; ++j) {
            int gj = tj * 128 + tx + 16 * j;
            Kp[(size_t)gi * NP + gj] = expf(acc[i][j] - 1.0f);
        }
    }
}

// ---------------------------------------------------------------- one Sinkhorn iteration
// Each block owns 32 rows of one problem's K. Reads each row ONCE into regs:
// uses it for the u-dot, then for the K^T u partials (column accumulators in
// registers). Cross-block combine via atomicAdd into vW. Triple-buffered
// v_acc: read R, write W, zero Z (no races).
__global__ __launch_bounds__(256) void k_sink(const float* __restrict__ K,
                                              float* __restrict__ u,
                                              const float* __restrict__ vR,
                                              float* __restrict__ vW,
                                              float* __restrict__ vZ,
                                              int first) {
    __shared__ float lds[4][NP];
    int bid  = blockIdx.x;        // 512 = 8 problems * 64 blocks
    int p    = bid >> 6;
    int blk  = bid & 63;
    int tid  = threadIdx.x;
    int w    = tid >> 6, lane = tid & 63;

    // zero the Z buffer slice (16384 floats / 512 blocks = 32 each)
    if (tid < 32) vZ[bid * 32 + tid] = 0.0f;

    // v values into registers: lane owns cols 4*(64c+lane)..+3 for c=0..7
    float4 vr[8];
    if (first) {
        #pragma unroll
        for (int c = 0; c < 8; ++c) vr[c] = make_float4(1.f, 1.f, 1.f, 1.f);
    } else {
        const float4* vRp = reinterpret_cast<const float4*>(vR + (size_t)p * NP);
        #pragma unroll
        for (int c = 0; c < 8; ++c) {
            float4 r4 = vRp[c * 64 + lane];
            vr[c] = make_float4(F_MU / (r4.x + F_STAB), F_MU / (r4.y + F_STAB),
                                F_MU / (r4.z + F_STAB), F_MU / (r4.w + F_STAB));
        }
    }

    const float* Kp = K + (size_t)p * NP * NP;
    float4 va[8];
    #pragma unroll
    for (int c = 0; c < 8; ++c) va[c] = make_float4(0.f, 0.f, 0.f, 0.f);

    int row0 = blk * 32 + w * 8;
    for (int r = 0; r < 8; ++r) {
        int row = row0 + r;
        const float4* krow = reinterpret_cast<const float4*>(Kp + (size_t)row * NP);
        float4 k4[8];
        #pragma unroll
        for (int c = 0; c < 8; ++c) k4[c] = krow[c * 64 + lane];
        float d = 0.f;
        #pragma unroll
        for (int c = 0; c < 8; ++c)
            d += k4[c].x * vr[c].x + k4[c].y * vr[c].y + k4[c].z * vr[c].z + k4[c].w * vr[c].w;
        #pragma unroll
        for (int off = 32; off; off >>= 1) d += __shfl_xor(d, off);
        float ui = F_MU / (d + F_STAB);
        if (lane == 0) u[p * NP + row] = ui;
        #pragma unroll
        for (int c = 0; c < 8; ++c) {
            va[c].x += k4[c].x * ui; va[c].y += k4[c].y * ui;
            va[c].z += k4[c].z * ui; va[c].w += k4[c].w * ui;
        }
    }

    // per-wave column accumulators -> LDS, combine 4 waves, atomic to global
    float4* lw = reinterpret_cast<float4*>(lds[w]);
    #pragma unroll
    for (int c = 0; c < 8; ++c) lw[c * 64 + lane] = va[c];
    __syncthreads();
    float* vWp = vW + (size_t)p * NP;
    const float4* l0 = reinterpret_cast<const float4*>(lds[0]);
    const float4* l1 = reinterpret_cast<const float4*>(lds[1]);
    const float4* l2 = reinterpret_cast<const float4*>(lds[2]);
    const float4* l3 = reinterpret_cast<const float4*>(lds[3]);
    #pragma unroll
    for (int s = 0; s < 2; ++s) {
        int j = tid + s * 256;    // 0..511 float4s
        float4 a0 = l0[j], a1 = l1[j], a2 = l2[j], a3 = l3[j];
        atomicAdd(&vWp[4 * j + 0], a0.x + a1.x + a2.x + a3.x);
        atomicAdd(&vWp[4 * j + 1], a0.y + a1.y + a2.y + a3.y);
        atomicAdd(&vWp[4 * j + 2], a0.z + a1.z + a2.z + a3.z);
        atomicAdd(&vWp[4 * j + 3], a0.w + a1.w + a2.w + a3.w);
    }
}

// ---------------------------------------------------------------- mean |f1-f2|
__global__ __launch_bounds__(256) void k_freduce(const float* __restrict__ K,
                                                 const float* __restrict__ u,
                                                 const float* __restrict__ vF,
                                                 float* __restrict__ sum) {
    int bid = blockIdx.x;        // 256 = 4 batches * 64 blocks
    int b   = bid >> 6;
    int blk = bid & 63;
    int tid = threadIdx.x;
    int w   = tid >> 6, lane = tid & 63;
    int p1 = b, p2 = 4 + b;

    float4 v1[8], v2[8];
    const float4* vF1 = reinterpret_cast<const float4*>(vF + (size_t)p1 * NP);
    const float4* vF2 = reinterpret_cast<const float4*>(vF + (size_t)p2 * NP);
    #pragma unroll
    for (int c = 0; c < 8; ++c) {
        float4 r1 = vF1[c * 64 + lane], r2 = vF2[c * 64 + lane];
        v1[c] = make_float4(F_MU / (r1.x + F_STAB), F_MU / (r1.y + F_STAB),
                            F_MU / (r1.z + F_STAB), F_MU / (r1.w + F_STAB));
        v2[c] = make_float4(F_MU / (r2.x + F_STAB), F_MU / (r2.y + F_STAB),
                            F_MU / (r2.z + F_STAB), F_MU / (r2.w + F_STAB));
    }
    const float* K1 = K + (size_t)p1 * NP * NP;
    const float* K2 = K + (size_t)p2 * NP * NP;
    float acc = 0.f;
    int row0 = blk * 32 + w * 8;
    for (int r = 0; r < 8; ++r) {
        int row = row0 + r;
        float u1 = u[p1 * NP + row], u2 = u[p2 * NP + row];
        const float4* k1 = reinterpret_cast<const float4*>(K1 + (size_t)row * NP);
        const float4* k2 = reinterpret_cast<const float4*>(K2 + (size_t)row * NP);
        #pragma unroll
        for (int c = 0; c < 8; ++c) {
            float4 a = k1[c * 64 + lane], bb = k2[c * 64 + lane];
            acc += fabsf(u1 * a.x * v1[c].x - u2 * bb.x * v2[c].x);
            acc += fabsf(u1 * a.y * v1[c].y - u2 * bb.y * v2[c].y);
            acc += fabsf(u1 * a.z * v1[c].z - u2 * bb.z * v2[c].z);
            acc += fabsf(u1 * a.w * v1[c].w - u2 * bb.w * v2[c].w);
        }
    }
    #pragma unroll
    for (int off = 32; off; off >>= 1) acc += __shfl_xor(acc, off);
    __shared__ float red[4];
    if (lane == 0) red[w] = acc;
    __syncthreads();
    if (tid == 0) atomicAdd(sum, red[0] + red[1] + red[2] + red[3]);
}

__global__ void k_final(const float* __restrict__ sum, float* __restrict__ out) {
    out[0] = sum[0] * (1.0f / 16777216.0f);   // / (4*2048*2048), exact 2^-24
}

// ---------------------------------------------------------------- launch
extern "C" void kernel_launch(void* const* d_in, const int* in_sizes, int n_in,
                              void* d_out, int out_size, void* d_ws, size_t ws_size,
                              hipStream_t stream) {
    const float* src = (const float*)d_in[0];
    const float* tgt = (const float*)d_in[1];
    const float* gen = (const float*)d_in[2];
    float* ws  = (float*)d_ws;
    float* Kw  = ws + OFF_K;
    float* va  = ws + OFF_VA;
    float* uu  = ws + OFF_U;
    float* inv = ws + OFF_INV;
    float* sum = ws + OFF_SUM;
    float* out = (float*)d_out;

    hipLaunchKernelGGL(k_norms, dim3(6144), dim3(256), 0, stream, src, tgt, gen, inv);
    hipLaunchKernelGGL(k_init,  dim3(65),   dim3(256), 0, stream, va, sum);
    hipLaunchKernelGGL(k_build, dim3(2048), dim3(256), 0, stream, src, tgt, gen, inv, Kw);
    for (int t = 0; t < 50; ++t) {
        float* R = va + ((size_t)((t + 2) % 3)) * (NPROB * NP);  // read (iter t-1 result)
        float* W = va + ((size_t)(t % 3))       * (NPROB * NP);  // accumulate
        float* Z = va + ((size_t)((t + 1) % 3)) * (NPROB * NP);  // zero for iter t+1
        hipLaunchKernelGGL(k_sink, dim3(512), dim3(256), 0, stream,
                           Kw, uu, R, W, Z, (t == 0) ? 1 : 0);
    }
    // final v is in buffer (49 % 3) == 1
    hipLaunchKernelGGL(k_freduce, dim3(256), dim3(256), 0, stream,
                       Kw, uu, va + (size_t)1 * (NPROB * NP), sum);
    hipLaunchKernelGGL(k_final, dim3(1), dim3(1), 0, stream, sum, out);
}